// Round 6
// baseline (1264.272 us; speedup 1.0000x reference)
//
#include <hip/hip_runtime.h>

#define TT   1024
#define TCH  128
#define SEQB 4        // sequences per block: 512 blocks -> 2 blocks/CU (R5: 8 seqs
                      // -> 256 blocks -> Occupancy 11.9% = 1 wave/SIMD, latency naked)

typedef __attribute__((ext_vector_type(8))) short short8;   // 8 bf16 (MFMA A/B frag)
typedef __attribute__((ext_vector_type(4))) short short4v;  // 4 bf16 = 8B
typedef __attribute__((ext_vector_type(4))) float f32x4;    // MFMA C/D frag

#define LOG2E 1.44269504088896340736f

__device__ __forceinline__ float sigf(float z) {
    return __builtin_amdgcn_rcpf(1.0f + __builtin_amdgcn_exp2f(-z * LOG2E));
}
__device__ __forceinline__ float tanhf_(float z) {
    return fmaf(-2.0f, __builtin_amdgcn_rcpf(1.0f + __builtin_amdgcn_exp2f(2.0f * LOG2E * z)), 1.0f);
}
__device__ __forceinline__ short bhi(float f) {
    return (short)(__builtin_bit_cast(unsigned, f) >> 16);
}
__device__ __forceinline__ float fhi(float f) {
    return __builtin_bit_cast(float, __builtin_bit_cast(unsigned, f) & 0xffff0000u);
}

// One block per (SEQB sequences, 1 direction). 4 waves; wave w owns z M-tiles
// {w,4+w,8+w,12+w} => lane holds i,f,g,o for the same (h-row, seq): c/h update
// in-register. z = Whh*h via mfma_f32_16x16x32_bf16, hi/lo split (3 products,
// two depth-3 chains per gate). FC reduce deferred one step (overlaps ds_read
// latency); drained by rotating wave at t+2.
__global__ __launch_bounds__(256, 2) void bilstm_mfma(
    const float* __restrict__ x,
    const float* __restrict__ Wih_f, const float* __restrict__ Whh_f,
    const float* __restrict__ bih_f, const float* __restrict__ bhh_f,
    const float* __restrict__ Wih_b, const float* __restrict__ Whh_b,
    const float* __restrict__ bih_b, const float* __restrict__ bhh_b,
    const float* __restrict__ fc_w, const float* __restrict__ fc_b,
    float* __restrict__ out)
{
    const int dir = blockIdx.x & 1;
    const int b0  = (blockIdx.x >> 1) * SEQB;
    const int tid  = threadIdx.x;
    const int w    = tid >> 6;
    const int lane = tid & 63;
    const int hb   = lane >> 4;   // K-chunk owner (A/B) / row-group (C/D)
    const int n    = lane & 15;   // seq column

    const float* __restrict__ Whh = dir ? Whh_b : Whh_f;
    const float* __restrict__ Wih = dir ? Wih_b : Wih_f;
    const float* __restrict__ bih = dir ? bih_b : bih_f;
    const float* __restrict__ bhh = dir ? bhh_b : bhh_f;

    __shared__ short Hlds[2][2][16][72];   // [buf][hi/lo][seq][h-row], 144B rows (16B-aligned)
    __shared__ float xs[16][TCH + 1];
    __shared__ float fcfb[2][16][4];       // [parity][seq][wave] FC partials

    // Zero H (both buffers) and the never-written xs rows SEQB..15.
    {
        unsigned* p1 = (unsigned*)&Hlds[0][0][0][0];
        for (int i = tid; i < 2 * 2 * 16 * 72 / 2; i += 256) p1[i] = 0u;
        float* p2 = &xs[SEQB][0];
        for (int i = tid; i < (16 - SEQB) * (TCH + 1); i += 256) p2[i] = 0.f;
    }

    // A-fragments: lane holds A[row=lane&15][k=8*(lane>>4)+e], hi/lo bf16 split.
    short8 ahi[4][2], alo[4][2];
#pragma unroll
    for (int s = 0; s < 4; ++s)
#pragma unroll
        for (int kt = 0; kt < 2; ++kt) {
            const int zrow = 64 * s + 16 * w + n;
            const float* p = Whh + zrow * 64 + 32 * kt + 8 * hb;
            const float4 u0 = *(const float4*)p;
            const float4 u1 = *(const float4*)(p + 4);
            float v[8] = {u0.x, u0.y, u0.z, u0.w, u1.x, u1.y, u1.z, u1.w};
            short8 h8, l8;
#pragma unroll
            for (int e = 0; e < 8; ++e) {
                h8[e] = bhi(v[e]);
                l8[e] = bhi(v[e] - fhi(v[e]));
            }
            ahi[s][kt] = h8;
            alo[s][kt] = l8;
        }

    f32x4 biasv[4], wihv[4], fcwv;
#pragma unroll
    for (int s = 0; s < 4; ++s)
#pragma unroll
        for (int r = 0; r < 4; ++r) {
            const int row = 64 * s + 16 * w + 4 * hb + r;
            biasv[s][r] = bih[row] + bhh[row];
            wihv[s][r]  = Wih[row];
        }
#pragma unroll
    for (int r = 0; r < 4; ++r) fcwv[r] = fc_w[dir * 64 + 16 * w + 4 * hb + r];
    const float fcbv = dir ? 0.f : fc_b[0];

    // Pin loop-invariant fragments (R3/R4: compiler otherwise re-sinks loads).
    asm volatile("" : "+v"(ahi[0][0]), "+v"(ahi[0][1]), "+v"(ahi[1][0]), "+v"(ahi[1][1]),
                      "+v"(ahi[2][0]), "+v"(ahi[2][1]), "+v"(ahi[3][0]), "+v"(ahi[3][1]),
                      "+v"(alo[0][0]), "+v"(alo[0][1]), "+v"(alo[1][0]), "+v"(alo[1][1]),
                      "+v"(alo[2][0]), "+v"(alo[2][1]), "+v"(alo[3][0]), "+v"(alo[3][1]));
    asm volatile("" : "+v"(biasv[0]), "+v"(biasv[1]), "+v"(biasv[2]), "+v"(biasv[3]),
                      "+v"(wihv[0]), "+v"(wihv[1]), "+v"(wihv[2]), "+v"(wihv[3]), "+v"(fcwv));

    // First x tile. Bwd consumes x reversed; out index stays t.
    for (int idx = tid; idx < SEQB * TCH; idx += 256) {
        const int s = idx >> 7, i = idx & (TCH - 1);
        const int src = dir ? (TT - 1 - i) : i;
        xs[s][i] = x[(size_t)(b0 + s) * TT + src];
    }
    __syncthreads();

    f32x4 c = {0.f, 0.f, 0.f, 0.f};
    float d_prev = 0.0f;
    int cur = 0;

#pragma unroll 1
    for (int t = 0; t < TT; ++t) {
        if (t && (t & (TCH - 1)) == 0) {   // refill x tile
            for (int idx = tid; idx < SEQB * TCH; idx += 256) {
                const int s = idx >> 7, i = idx & (TCH - 1);
                const int tg = t + i;
                const int src = dir ? (TT - 1 - tg) : tg;
                xs[s][i] = x[(size_t)(b0 + s) * TT + src];
            }
            __syncthreads();
        }

        // B-fragments for this step (h written last step, visible post-barrier).
        short8 Bf[2][2];
#pragma unroll
        for (int kt = 0; kt < 2; ++kt)
#pragma unroll
            for (int pp = 0; pp < 2; ++pp)
                Bf[kt][pp] = *(const short8*)&Hlds[cur][pp][n][32 * kt + 8 * hb];

        // Deferred FC finish for h(t-1): overlaps Bf ds_read latency.
        if (t >= 1) {
            float d = d_prev;
            d += __shfl_xor(d, 16);
            d += __shfl_xor(d, 32);
            if (lane < 16) fcfb[(t - 1) & 1][lane][w] = d;
        }
        // Drain out[b, t-2] (rotating wave; fcfb[(t-2)&1] == fcfb[t&1] visible
        // since end-of-(t-1) barrier).
        if (t >= 2 && w == (t & 3) && lane < SEQB) {
            const float4 fp = *(const float4*)&fcfb[t & 1][lane][0];
            atomicAdd(out + (size_t)(b0 + lane) * TT + (t - 2),
                      fp.x + fp.y + fp.z + fp.w + fcbv);
        }

        const float xt = xs[n][t & (TCH - 1)];

        // Two depth-3 MFMA chains per gate (R5 had one depth-6 chain).
        f32x4 acc0, acc1, acc2, acc3;
#define ZCHAIN(ACC, S)                                                                    \
        ACC[0] = fmaf(xt, wihv[S][0], biasv[S][0]);                                       \
        ACC[1] = fmaf(xt, wihv[S][1], biasv[S][1]);                                       \
        ACC[2] = fmaf(xt, wihv[S][2], biasv[S][2]);                                       \
        ACC[3] = fmaf(xt, wihv[S][3], biasv[S][3]);                                       \
        {                                                                                 \
            f32x4 q = {0.f, 0.f, 0.f, 0.f};                                               \
            ACC = __builtin_amdgcn_mfma_f32_16x16x32_bf16(ahi[S][0], Bf[0][0], ACC, 0, 0, 0); \
            q   = __builtin_amdgcn_mfma_f32_16x16x32_bf16(ahi[S][1], Bf[1][0], q,   0, 0, 0); \
            ACC = __builtin_amdgcn_mfma_f32_16x16x32_bf16(ahi[S][0], Bf[0][1], ACC, 0, 0, 0); \
            q   = __builtin_amdgcn_mfma_f32_16x16x32_bf16(ahi[S][1], Bf[1][1], q,   0, 0, 0); \
            ACC = __builtin_amdgcn_mfma_f32_16x16x32_bf16(alo[S][0], Bf[0][0], ACC, 0, 0, 0); \
            q   = __builtin_amdgcn_mfma_f32_16x16x32_bf16(alo[S][1], Bf[1][0], q,   0, 0, 0); \
            ACC[0] += q[0]; ACC[1] += q[1]; ACC[2] += q[2]; ACC[3] += q[3];               \
        }
        ZCHAIN(acc0, 0)   // gate i
        ZCHAIN(acc1, 1)   // gate f
        ZCHAIN(acc2, 2)   // gate g
        ZCHAIN(acc3, 3)   // gate o
#undef ZCHAIN

        // Gates + state update, in-register.
        f32x4 hnew;
        short4v ph, pl;
#pragma unroll
        for (int r = 0; r < 4; ++r) {
            const float gi = sigf(acc0[r]);
            const float gf = sigf(acc1[r]);
            const float gg = tanhf_(acc2[r]);
            const float go = sigf(acc3[r]);
            c[r] = fmaf(gf, c[r], gi * gg);
            const float hv = go * tanhf_(c[r]);
            hnew[r] = hv;
            ph[r] = bhi(hv);
            pl[r] = bhi(hv - fhi(hv));
        }
        const int nxt = cur ^ 1;
        *(short4v*)&Hlds[nxt][0][n][16 * w + 4 * hb] = ph;
        *(short4v*)&Hlds[nxt][1][n][16 * w + 4 * hb] = pl;

        // FC lane-partial only; shuffle-reduce deferred to next step's front.
        d_prev = hnew[0] * fcwv[0] + hnew[1] * fcwv[1] + hnew[2] * fcwv[2] + hnew[3] * fcwv[3];

        __syncthreads();
        cur = nxt;
    }

    // Epilogue: finish FC for t=TT-1; drain out[.., TT-2] and [.., TT-1].
    {
        float d = d_prev;
        d += __shfl_xor(d, 16);
        d += __shfl_xor(d, 32);
        if (lane < 16) fcfb[(TT - 1) & 1][lane][w] = d;
        if (w == 1 && lane < SEQB) {            // (TT-2)&1 == 0 slot, visible since last barrier
            const float4 fp = *(const float4*)&fcfb[(TT - 2) & 1][lane][0];
            atomicAdd(out + (size_t)(b0 + lane) * TT + (TT - 2),
                      fp.x + fp.y + fp.z + fp.w + fcbv);
        }
        __syncthreads();
        if (w == 0 && lane < SEQB) {
            const float4 fp = *(const float4*)&fcfb[(TT - 1) & 1][lane][0];
            atomicAdd(out + (size_t)(b0 + lane) * TT + (TT - 1),
                      fp.x + fp.y + fp.z + fp.w + fcbv);
        }
    }
}

extern "C" void kernel_launch(void* const* d_in, const int* in_sizes, int n_in,
                              void* d_out, int out_size, void* d_ws, size_t ws_size,
                              hipStream_t stream) {
    const float* xp    = (const float*)d_in[0];
    const float* Wih_f = (const float*)d_in[1];
    const float* Whh_f = (const float*)d_in[2];
    const float* bih_f = (const float*)d_in[3];
    const float* bhh_f = (const float*)d_in[4];
    const float* Wih_b = (const float*)d_in[5];
    const float* Whh_b = (const float*)d_in[6];
    const float* bih_b = (const float*)d_in[7];
    const float* bhh_b = (const float*)d_in[8];
    const float* fc_w  = (const float*)d_in[9];
    const float* fc_b  = (const float*)d_in[10];
    float* outp = (float*)d_out;

    // Both direction-blocks atomicAdd into out: zero it first (capture-safe).
    hipMemsetAsync(d_out, 0, (size_t)out_size * sizeof(float), stream);

    bilstm_mfma<<<dim3((1024 / SEQB) * 2), dim3(256), 0, stream>>>(
        xp, Wih_f, Whh_f, bih_f, bhh_f,
        Wih_b, Whh_b, bih_b, bhh_b, fc_w, fc_b, outp);
}

// Round 7
// 875.768 us; speedup vs baseline: 1.4436x; 1.4436x over previous
//
#include <hip/hip_runtime.h>

#define TT   1024
#define SEQB 8        // 256 blocks = 1/CU. R6 lesson: >256 blocks forces MFMA
                      // N-waste per useful slot; co-scheduled dup work regressed 1.7x.

typedef __attribute__((ext_vector_type(8))) short short8;   // 8 bf16 (MFMA A/B frag)
typedef __attribute__((ext_vector_type(4))) short short4v;  // 4 bf16 = 8B
typedef __attribute__((ext_vector_type(4))) float f32x4;    // MFMA C/D frag

#define LOG2E 1.44269504088896340736f

__device__ __forceinline__ float sigf(float z) {
    return __builtin_amdgcn_rcpf(1.0f + __builtin_amdgcn_exp2f(-z * LOG2E));
}
__device__ __forceinline__ float tanhf_(float z) {
    return fmaf(-2.0f, __builtin_amdgcn_rcpf(1.0f + __builtin_amdgcn_exp2f(2.0f * LOG2E * z)), 1.0f);
}
__device__ __forceinline__ short bhi(float f) {
    return (short)(__builtin_bit_cast(unsigned, f) >> 16);
}
__device__ __forceinline__ float fhi(float f) {
    return __builtin_bit_cast(float, __builtin_bit_cast(unsigned, f) & 0xffff0000u);
}

// One block per (8 sequences, 1 direction): 256 blocks, 4 waves, 1 block/CU.
// Wave w owns z M-tiles {w,4+w,8+w,12+w}: lane holds i,f,g,o for the same
// (h-row, seq) -> c/h update fully in-register. z = Whh*h via
// mfma_f32_16x16x32_bf16 hi/lo split (3 products, two depth-3 chains/gate).
// Whole x in LDS (no refill barriers). FC reduce deferred 1 step; drained at
// t+2 by a rotating wave. Unroll-2 with static double-buffer indices.
__global__ __launch_bounds__(256, 1) void bilstm_mfma(
    const float* __restrict__ x,
    const float* __restrict__ Wih_f, const float* __restrict__ Whh_f,
    const float* __restrict__ bih_f, const float* __restrict__ bhh_f,
    const float* __restrict__ Wih_b, const float* __restrict__ Whh_b,
    const float* __restrict__ bih_b, const float* __restrict__ bhh_b,
    const float* __restrict__ fc_w, const float* __restrict__ fc_b,
    float* __restrict__ out)
{
    const int dir = blockIdx.x & 1;
    const int b0  = (blockIdx.x >> 1) * SEQB;
    const int tid  = threadIdx.x;
    const int w    = tid >> 6;
    const int lane = tid & 63;
    const int hb   = lane >> 4;   // K-chunk owner (A/B) / row-group (C/D)
    const int n    = lane & 15;   // seq column (n>=8: quarantined garbage cols)

    const float* __restrict__ Whh = dir ? Whh_b : Whh_f;
    const float* __restrict__ Wih = dir ? Wih_b : Wih_f;
    const float* __restrict__ bih = dir ? bih_b : bih_f;
    const float* __restrict__ bhh = dir ? bhh_b : bhh_f;

    __shared__ short Hlds[2][2][16][72];   // [buf][hi/lo][seq][h-row], 144B rows
    __shared__ float xs[SEQB][TT + 1];     // stride 1025: conflict-free column read
    __shared__ float fcfb[2][16][4];       // [parity][seq][wave] FC partials

    // Zero both H buffers (t=0 reads buf 0; buf 1 for safety).
    {
        unsigned* p1 = (unsigned*)&Hlds[0][0][0][0];
        for (int i = tid; i < 2 * 2 * 16 * 72 / 2; i += 256) p1[i] = 0u;
    }

    // Whole x for this block's 8 seqs (32 KB). Bwd consumes x reversed.
    for (int idx = tid; idx < SEQB * TT; idx += 256) {
        const int s = idx >> 10, i = idx & (TT - 1);
        const int src = dir ? (TT - 1 - i) : i;
        xs[s][i] = x[(size_t)(b0 + s) * TT + src];
    }

    // A-fragments: lane holds A[row=lane&15][k=8*(lane>>4)+e], hi/lo bf16 split.
    short8 ahi[4][2], alo[4][2];
#pragma unroll
    for (int s = 0; s < 4; ++s)
#pragma unroll
        for (int kt = 0; kt < 2; ++kt) {
            const int zrow = 64 * s + 16 * w + n;
            const float* p = Whh + zrow * 64 + 32 * kt + 8 * hb;
            const float4 u0 = *(const float4*)p;
            const float4 u1 = *(const float4*)(p + 4);
            float v[8] = {u0.x, u0.y, u0.z, u0.w, u1.x, u1.y, u1.z, u1.w};
            short8 h8, l8;
#pragma unroll
            for (int e = 0; e < 8; ++e) {
                h8[e] = bhi(v[e]);
                l8[e] = bhi(v[e] - fhi(v[e]));
            }
            ahi[s][kt] = h8;
            alo[s][kt] = l8;
        }

    f32x4 biasv[4], wihv[4], fcwv;
#pragma unroll
    for (int s = 0; s < 4; ++s)
#pragma unroll
        for (int r = 0; r < 4; ++r) {
            const int row = 64 * s + 16 * w + 4 * hb + r;
            biasv[s][r] = bih[row] + bhh[row];
            wihv[s][r]  = Wih[row];
        }
#pragma unroll
    for (int r = 0; r < 4; ++r) fcwv[r] = fc_w[dir * 64 + 16 * w + 4 * hb + r];
    const float fcbv = dir ? 0.f : fc_b[0];

    // Pin loop-invariant fragments (R3/R4: compiler otherwise re-sinks loads).
    asm volatile("" : "+v"(ahi[0][0]), "+v"(ahi[0][1]), "+v"(ahi[1][0]), "+v"(ahi[1][1]),
                      "+v"(ahi[2][0]), "+v"(ahi[2][1]), "+v"(ahi[3][0]), "+v"(ahi[3][1]),
                      "+v"(alo[0][0]), "+v"(alo[0][1]), "+v"(alo[1][0]), "+v"(alo[1][1]),
                      "+v"(alo[2][0]), "+v"(alo[2][1]), "+v"(alo[3][0]), "+v"(alo[3][1]));
    asm volatile("" : "+v"(biasv[0]), "+v"(biasv[1]), "+v"(biasv[2]), "+v"(biasv[3]),
                      "+v"(wihv[0]), "+v"(wihv[1]), "+v"(wihv[2]), "+v"(wihv[3]), "+v"(fcwv));

    __syncthreads();

    f32x4 c = {0.f, 0.f, 0.f, 0.f};
    float d_prev = 0.0f;
    const int nx = n & 7;   // garbage cols n>=8 mirror a real seq's x: finite, quarantined

    float* __restrict__ outb = out + (size_t)b0 * TT;

#define STEPBODY(tv, CUR)                                                                 \
    {                                                                                     \
        const int t_ = (tv);                                                              \
        /* B-frags for this step (h(t-1), visible since last barrier). */                 \
        short8 Bf[2][2];                                                                  \
        _Pragma("unroll")                                                                 \
        for (int kt = 0; kt < 2; ++kt)                                                    \
            _Pragma("unroll")                                                             \
            for (int pp = 0; pp < 2; ++pp)                                                \
                Bf[kt][pp] = *(const short8*)&Hlds[CUR][pp][n][32 * kt + 8 * hb];         \
        /* Deferred FC finish for h(t-1): overlaps Bf ds_read latency. */                 \
        if (t_ >= 1) {                                                                    \
            float d = d_prev;                                                             \
            d += __shfl_xor(d, 16);                                                       \
            d += __shfl_xor(d, 32);                                                       \
            if (lane < 16) fcfb[(t_ - 1) & 1][lane][w] = d;                               \
        }                                                                                 \
        /* Drain out[b, t-2] (rotating wave; fcfb[t&1] written at step t-1). */           \
        if (t_ >= 2 && w == (t_ & 3) && lane < SEQB) {                                    \
            const float4 fp = *(const float4*)&fcfb[t_ & 1][lane][0];                     \
            atomicAdd(outb + (size_t)lane * TT + (t_ - 2),                                \
                      fp.x + fp.y + fp.z + fp.w + fcbv);                                  \
        }                                                                                 \
        const float xt = xs[nx][t_];                                                      \
        f32x4 acc0, acc1, acc2, acc3;                                                     \
        ZCHAIN(acc0, 0) ZCHAIN(acc1, 1) ZCHAIN(acc2, 2) ZCHAIN(acc3, 3)                   \
        /* Gates + state update, in-register. */                                          \
        f32x4 hnew;                                                                       \
        short4v ph, pl;                                                                   \
        _Pragma("unroll")                                                                 \
        for (int r = 0; r < 4; ++r) {                                                     \
            const float gi = sigf(acc0[r]);                                               \
            const float gf = sigf(acc1[r]);                                               \
            const float gg = tanhf_(acc2[r]);                                             \
            const float go = sigf(acc3[r]);                                               \
            c[r] = fmaf(gf, c[r], gi * gg);                                               \
            const float hv = go * tanhf_(c[r]);                                           \
            hnew[r] = hv;                                                                 \
            ph[r] = bhi(hv);                                                              \
            pl[r] = bhi(hv - fhi(hv));                                                    \
        }                                                                                 \
        /* Publish h early (write drains while FC partial computes). */                   \
        *(short4v*)&Hlds[(CUR) ^ 1][0][n][16 * w + 4 * hb] = ph;                          \
        *(short4v*)&Hlds[(CUR) ^ 1][1][n][16 * w + 4 * hb] = pl;                          \
        d_prev = hnew[0] * fcwv[0] + hnew[1] * fcwv[1]                                    \
               + hnew[2] * fcwv[2] + hnew[3] * fcwv[3];                                   \
        __syncthreads();                                                                  \
    }

#define ZCHAIN(ACC, S)                                                                    \
        ACC[0] = fmaf(xt, wihv[S][0], biasv[S][0]);                                       \
        ACC[1] = fmaf(xt, wihv[S][1], biasv[S][1]);                                       \
        ACC[2] = fmaf(xt, wihv[S][2], biasv[S][2]);                                       \
        ACC[3] = fmaf(xt, wihv[S][3], biasv[S][3]);                                       \
        {                                                                                 \
            f32x4 q = {0.f, 0.f, 0.f, 0.f};                                               \
            ACC = __builtin_amdgcn_mfma_f32_16x16x32_bf16(ahi[S][0], Bf[0][0], ACC, 0, 0, 0); \
            q   = __builtin_amdgcn_mfma_f32_16x16x32_bf16(ahi[S][1], Bf[1][0], q,   0, 0, 0); \
            ACC = __builtin_amdgcn_mfma_f32_16x16x32_bf16(ahi[S][0], Bf[0][1], ACC, 0, 0, 0); \
            q   = __builtin_amdgcn_mfma_f32_16x16x32_bf16(ahi[S][1], Bf[1][1], q,   0, 0, 0); \
            ACC = __builtin_amdgcn_mfma_f32_16x16x32_bf16(alo[S][0], Bf[0][0], ACC, 0, 0, 0); \
            q   = __builtin_amdgcn_mfma_f32_16x16x32_bf16(alo[S][1], Bf[1][0], q,   0, 0, 0); \
            ACC[0] += q[0]; ACC[1] += q[1]; ACC[2] += q[2]; ACC[3] += q[3];               \
        }

#pragma unroll 1
    for (int t = 0; t < TT; t += 2) {
        STEPBODY(t, 0)
        STEPBODY(t + 1, 1)
    }
#undef STEPBODY
#undef ZCHAIN

    // Epilogue: finish FC for t=TT-1; drain out[.., TT-2] and [.., TT-1].
    {
        float d = d_prev;
        d += __shfl_xor(d, 16);
        d += __shfl_xor(d, 32);
        if (lane < 16) fcfb[(TT - 1) & 1][lane][w] = d;
        if (w == 1 && lane < SEQB) {   // fcfb[(TT-2)&1] written at step TT-1, visible
            const float4 fp = *(const float4*)&fcfb[(TT - 2) & 1][lane][0];
            atomicAdd(outb + (size_t)lane * TT + (TT - 2),
                      fp.x + fp.y + fp.z + fp.w + fcbv);
        }
        __syncthreads();
        if (w == 0 && lane < SEQB) {
            const float4 fp = *(const float4*)&fcfb[(TT - 1) & 1][lane][0];
            atomicAdd(outb + (size_t)lane * TT + (TT - 1),
                      fp.x + fp.y + fp.z + fp.w + fcbv);
        }
    }
}

extern "C" void kernel_launch(void* const* d_in, const int* in_sizes, int n_in,
                              void* d_out, int out_size, void* d_ws, size_t ws_size,
                              hipStream_t stream) {
    const float* xp    = (const float*)d_in[0];
    const float* Wih_f = (const float*)d_in[1];
    const float* Whh_f = (const float*)d_in[2];
    const float* bih_f = (const float*)d_in[3];
    const float* bhh_f = (const float*)d_in[4];
    const float* Wih_b = (const float*)d_in[5];
    const float* Whh_b = (const float*)d_in[6];
    const float* bih_b = (const float*)d_in[7];
    const float* bhh_b = (const float*)d_in[8];
    const float* fc_w  = (const float*)d_in[9];
    const float* fc_b  = (const float*)d_in[10];
    float* outp = (float*)d_out;

    // Both direction-blocks atomicAdd into out: zero it first (capture-safe).
    hipMemsetAsync(d_out, 0, (size_t)out_size * sizeof(float), stream);

    bilstm_mfma<<<dim3((1024 / SEQB) * 2), dim3(256), 0, stream>>>(
        xp, Wih_f, Whh_f, bih_f, bhh_f,
        Wih_b, Whh_b, bih_b, bhh_b, fc_w, fc_b, outp);
}

// Round 8
// 873.691 us; speedup vs baseline: 1.4470x; 1.0024x over previous
//
#include <hip/hip_runtime.h>

#define TT   1024
#define SEQB 8        // 256 blocks = 1/CU (R6: >256 blocks duplicates chip issue, 1.7x loss)

typedef __attribute__((ext_vector_type(8))) short short8;   // 8 bf16 (MFMA A/B frag)
typedef __attribute__((ext_vector_type(4))) short short4v;  // 4 bf16 = 8B
typedef __attribute__((ext_vector_type(4))) float f32x4;    // MFMA C/D frag

#define LOG2E 1.44269504088896340736f

__device__ __forceinline__ float sigf(float z) {
    return __builtin_amdgcn_rcpf(1.0f + __builtin_amdgcn_exp2f(-z * LOG2E));
}
__device__ __forceinline__ float tanhf_(float z) {
    return fmaf(-2.0f, __builtin_amdgcn_rcpf(1.0f + __builtin_amdgcn_exp2f(2.0f * LOG2E * z)), 1.0f);
}
__device__ __forceinline__ short bhi(float f) {
    return (short)(__builtin_bit_cast(unsigned, f) >> 16);
}
__device__ __forceinline__ float fhi(float f) {
    return __builtin_bit_cast(float, __builtin_bit_cast(unsigned, f) & 0xffff0000u);
}

// 256 blocks (8 seqs x 1 dir), 512 threads = 8 waves = 2 waves/SIMD at
// CONSERVED chip issue (R6 lesson: extra blocks duplicate issue; extra waves
// splitting the same tiles don't). Low waves w=0..3 own gates i,g (M-tiles
// {w, 8+w}); high waves w=4..7 own f,o (tiles {4+w', 12+w'}) for the SAME
// h-rows. P = sig(i)*tanh(g) crosses low->high via LDS once per step; high
// owns c/h update + FC partial; low drains the t-1 atomicAdd.
__global__ __launch_bounds__(512, 1) void bilstm_mfma8(
    const float* __restrict__ x,
    const float* __restrict__ Wih_f, const float* __restrict__ Whh_f,
    const float* __restrict__ bih_f, const float* __restrict__ bhh_f,
    const float* __restrict__ Wih_b, const float* __restrict__ Whh_b,
    const float* __restrict__ bih_b, const float* __restrict__ bhh_b,
    const float* __restrict__ fc_w, const float* __restrict__ fc_b,
    float* __restrict__ out)
{
    const int dir = blockIdx.x & 1;
    const int b0  = (blockIdx.x >> 1) * SEQB;
    const int tid  = threadIdx.x;
    const int w    = tid >> 6;          // 0..7
    const int lane = tid & 63;
    const int hb   = lane >> 4;         // K-chunk owner (A/B) / row-group (C/D)
    const int n    = lane & 15;         // seq column (n>=8: quarantined garbage)
    const bool low = (w < 4);
    const int wp   = low ? w : (w - 4); // pair index 0..3

    // M-tiles: low -> {wp (gate i), 8+wp (gate g)}; high -> {4+wp (f), 12+wp (o)}
    const int tile0 = low ? wp       : (4 + wp);
    const int tile1 = low ? (8 + wp) : (12 + wp);

    const float* __restrict__ Whh = dir ? Whh_b : Whh_f;
    const float* __restrict__ Wih = dir ? Wih_b : Wih_f;
    const float* __restrict__ bih = dir ? bih_b : bih_f;
    const float* __restrict__ bhh = dir ? bhh_b : bhh_f;

    __shared__ short Hlds[2][2][16][72];   // [buf][hi/lo][seq][h-row], 144B rows
    __shared__ float xs[SEQB][TT + 1];     // stride 1025: conflict-free
    __shared__ float Pbuf[16][68];         // [seq][h-row pad 68]: low->high P
    __shared__ float fcfb[2][16][4];       // [parity][seq][high-wave] FC partials

    // Zero both H buffers.
    for (int i = tid; i < 2 * 2 * 16 * 72 / 2; i += 512) ((unsigned*)Hlds)[i] = 0u;

    // Whole x for this block's 8 seqs (32.8 KB). Bwd consumes x reversed.
    for (int idx = tid; idx < SEQB * TT; idx += 512) {
        const int s = idx >> 10, i = idx & (TT - 1);
        const int src = dir ? (TT - 1 - i) : i;
        xs[s][i] = x[(size_t)(b0 + s) * TT + src];
    }

    // A-frags for this wave's two tiles: lane holds A[row=n][k=8*hb+e], hi/lo split.
    short8 ahi[2][2], alo[2][2];
#pragma unroll
    for (int S = 0; S < 2; ++S) {
        const int tile = S ? tile1 : tile0;
#pragma unroll
        for (int kt = 0; kt < 2; ++kt) {
            const int zrow = 16 * tile + n;
            const float* p = Whh + zrow * 64 + 32 * kt + 8 * hb;
            const float4 u0 = *(const float4*)p;
            const float4 u1 = *(const float4*)(p + 4);
            float v[8] = {u0.x, u0.y, u0.z, u0.w, u1.x, u1.y, u1.z, u1.w};
            short8 h8, l8;
#pragma unroll
            for (int e = 0; e < 8; ++e) {
                h8[e] = bhi(v[e]);
                l8[e] = bhi(v[e] - fhi(v[e]));
            }
            ahi[S][kt] = h8;
            alo[S][kt] = l8;
        }
    }

    f32x4 biasv[2], wihv[2], fcwv;
#pragma unroll
    for (int S = 0; S < 2; ++S) {
        const int tile = S ? tile1 : tile0;
#pragma unroll
        for (int r = 0; r < 4; ++r) {
            const int row = 16 * tile + 4 * hb + r;
            biasv[S][r] = bih[row] + bhh[row];
            wihv[S][r]  = Wih[row];
        }
    }
#pragma unroll
    for (int r = 0; r < 4; ++r)
        fcwv[r] = fc_w[dir * 64 + 16 * wp + 4 * hb + r];   // high waves' h-rows
    const float fcbv = dir ? 0.f : fc_b[0];

    // Pin loop-invariants (R3/R4: compiler otherwise re-sinks the loads).
    asm volatile("" : "+v"(ahi[0][0]), "+v"(ahi[0][1]), "+v"(ahi[1][0]), "+v"(ahi[1][1]),
                      "+v"(alo[0][0]), "+v"(alo[0][1]), "+v"(alo[1][0]), "+v"(alo[1][1]));
    asm volatile("" : "+v"(biasv[0]), "+v"(biasv[1]),
                      "+v"(wihv[0]), "+v"(wihv[1]), "+v"(fcwv));

    __syncthreads();

    f32x4 c = {0.f, 0.f, 0.f, 0.f};
    f32x4 Fg = {0.f, 0.f, 0.f, 0.f}, Og = {0.f, 0.f, 0.f, 0.f};
    float d_prev = 0.0f;
    const int nx = n & 7;
    int cur = 0;
    float* __restrict__ outb = out + (size_t)b0 * TT;

#pragma unroll 1
    for (int t = 0; t < TT; ++t) {
        // B-frags (h(t-1), visible since last barrier). Both halves need them.
        short8 Bf[2][2];
#pragma unroll
        for (int kt = 0; kt < 2; ++kt)
#pragma unroll
            for (int pp = 0; pp < 2; ++pp)
                Bf[kt][pp] = *(const short8*)&Hlds[cur][pp][n][32 * kt + 8 * hb];

        const float xt = xs[nx][t];

        f32x4 acc0, acc1;
#define ZCHAIN(ACC, S)                                                                    \
        ACC[0] = fmaf(xt, wihv[S][0], biasv[S][0]);                                       \
        ACC[1] = fmaf(xt, wihv[S][1], biasv[S][1]);                                       \
        ACC[2] = fmaf(xt, wihv[S][2], biasv[S][2]);                                       \
        ACC[3] = fmaf(xt, wihv[S][3], biasv[S][3]);                                       \
        {                                                                                 \
            f32x4 q = {0.f, 0.f, 0.f, 0.f};                                               \
            ACC = __builtin_amdgcn_mfma_f32_16x16x32_bf16(ahi[S][0], Bf[0][0], ACC, 0, 0, 0); \
            q   = __builtin_amdgcn_mfma_f32_16x16x32_bf16(ahi[S][1], Bf[1][0], q,   0, 0, 0); \
            ACC = __builtin_amdgcn_mfma_f32_16x16x32_bf16(ahi[S][0], Bf[0][1], ACC, 0, 0, 0); \
            q   = __builtin_amdgcn_mfma_f32_16x16x32_bf16(ahi[S][1], Bf[1][1], q,   0, 0, 0); \
            ACC = __builtin_amdgcn_mfma_f32_16x16x32_bf16(alo[S][0], Bf[0][0], ACC, 0, 0, 0); \
            q   = __builtin_amdgcn_mfma_f32_16x16x32_bf16(alo[S][1], Bf[1][0], q,   0, 0, 0); \
            ACC[0] += q[0]; ACC[1] += q[1]; ACC[2] += q[2]; ACC[3] += q[3];               \
        }
        ZCHAIN(acc0, 0)
        ZCHAIN(acc1, 1)
#undef ZCHAIN

        if (low) {
            // P = sig(z_i) * tanh(z_g) -> LDS for the partner wave.
            f32x4 P;
#pragma unroll
            for (int r = 0; r < 4; ++r) P[r] = sigf(acc0[r]) * tanhf_(acc1[r]);
            *(f32x4*)&Pbuf[n][16 * wp + 4 * hb] = P;
        } else {
#pragma unroll
            for (int r = 0; r < 4; ++r) { Fg[r] = sigf(acc0[r]); Og[r] = sigf(acc1[r]); }
            // Deferred FC finish for h(t-1): overlaps the MFMA/trans phase.
            if (t >= 1) {
                float d = d_prev;
                d += __shfl_xor(d, 16);
                d += __shfl_xor(d, 32);
                if (lane < 16) fcfb[(t - 1) & 1][lane][wp] = d;
            }
        }
        __syncthreads();

        if (!low) {
            const f32x4 P = *(const f32x4*)&Pbuf[n][16 * wp + 4 * hb];
            f32x4 hnew;
            short4v ph, pl;
#pragma unroll
            for (int r = 0; r < 4; ++r) {
                c[r] = fmaf(Fg[r], c[r], P[r]);
                const float hv = Og[r] * tanhf_(c[r]);
                hnew[r] = hv;
                ph[r] = bhi(hv);
                pl[r] = bhi(hv - fhi(hv));
            }
            *(short4v*)&Hlds[cur ^ 1][0][n][16 * wp + 4 * hb] = ph;
            *(short4v*)&Hlds[cur ^ 1][1][n][16 * wp + 4 * hb] = pl;
            d_prev = hnew[0] * fcwv[0] + hnew[1] * fcwv[1]
                   + hnew[2] * fcwv[2] + hnew[3] * fcwv[3];
        } else if (t >= 1 && w == (t & 3) && lane < SEQB) {
            // Drain out[b, t-1] (fcfb written by high waves before the barrier).
            const float4 fp = *(const float4*)&fcfb[(t - 1) & 1][lane][0];
            atomicAdd(outb + (size_t)lane * TT + (t - 1),
                      fp.x + fp.y + fp.z + fp.w + fcbv);
        }
        __syncthreads();
        cur ^= 1;
    }

    // Epilogue: reduce + drain t = TT-1.
    if (!low) {
        float d = d_prev;
        d += __shfl_xor(d, 16);
        d += __shfl_xor(d, 32);
        if (lane < 16) fcfb[(TT - 1) & 1][lane][wp] = d;
    }
    __syncthreads();
    if (w == 0 && lane < SEQB) {
        const float4 fp = *(const float4*)&fcfb[(TT - 1) & 1][lane][0];
        atomicAdd(outb + (size_t)lane * TT + (TT - 1),
                  fp.x + fp.y + fp.z + fp.w + fcbv);
    }
}

extern "C" void kernel_launch(void* const* d_in, const int* in_sizes, int n_in,
                              void* d_out, int out_size, void* d_ws, size_t ws_size,
                              hipStream_t stream) {
    const float* xp    = (const float*)d_in[0];
    const float* Wih_f = (const float*)d_in[1];
    const float* Whh_f = (const float*)d_in[2];
    const float* bih_f = (const float*)d_in[3];
    const float* bhh_f = (const float*)d_in[4];
    const float* Wih_b = (const float*)d_in[5];
    const float* Whh_b = (const float*)d_in[6];
    const float* bih_b = (const float*)d_in[7];
    const float* bhh_b = (const float*)d_in[8];
    const float* fc_w  = (const float*)d_in[9];
    const float* fc_b  = (const float*)d_in[10];
    float* outp = (float*)d_out;

    // Both direction-blocks atomicAdd into out: zero it first (capture-safe).
    hipMemsetAsync(d_out, 0, (size_t)out_size * sizeof(float), stream);

    bilstm_mfma8<<<dim3((1024 / SEQB) * 2), dim3(512), 0, stream>>>(
        xp, Wih_f, Whh_f, bih_f, bhh_f,
        Wih_b, Whh_b, bih_b, bhh_b, fc_w, fc_b, outp);
}

// Round 9
// 788.342 us; speedup vs baseline: 1.6037x; 1.1083x over previous
//
#include <hip/hip_runtime.h>

#define TT   1024
#define TCH  128
#define SEQB 8        // 256 blocks = 1/CU. R6: more blocks duplicates issue (1.7x loss);
                      // R8: more waves in one barrier domain run lockstep (null).

typedef __attribute__((ext_vector_type(8))) short short8;   // 8 bf16 (MFMA A/B frag)
typedef __attribute__((ext_vector_type(4))) short short4v;  // 4 bf16 = 8B
typedef __attribute__((ext_vector_type(4))) float f32x4;    // MFMA C/D frag

#define LOG2E 1.44269504088896340736f

__device__ __forceinline__ float sigf(float z) {
    return __builtin_amdgcn_rcpf(1.0f + __builtin_amdgcn_exp2f(-z * LOG2E));
}
__device__ __forceinline__ float tanhf_(float z) {
    return fmaf(-2.0f, __builtin_amdgcn_rcpf(1.0f + __builtin_amdgcn_exp2f(2.0f * LOG2E * z)), 1.0f);
}
__device__ __forceinline__ short bhi(float f) {
    return (short)(__builtin_bit_cast(unsigned, f) >> 16);
}
__device__ __forceinline__ float fhi(float f) {
    return __builtin_bit_cast(float, __builtin_bit_cast(unsigned, f) & 0xffff0000u);
}

// R5 structure (805us anchor) with ONE change: no vmem inside the t-loop.
// R5/R7/R8 all paid a per-step global atomicAdd whose write-ack is drained by
// __syncthreads' s_waitcnt vmcnt(0) -> ~500-900 cyc/step whole-block stall.
// FC outputs now accumulate in LDS (os[seq][t]); epilogue bulk-stores them
// (fwd->out, bwd->ws) and a tiny add kernel sums the directions.
__global__ __launch_bounds__(256, 2) void bilstm_mfma(
    const float* __restrict__ x,
    const float* __restrict__ Wih_f, const float* __restrict__ Whh_f,
    const float* __restrict__ bih_f, const float* __restrict__ bhh_f,
    const float* __restrict__ Wih_b, const float* __restrict__ Whh_b,
    const float* __restrict__ bih_b, const float* __restrict__ bhh_b,
    const float* __restrict__ fc_w, const float* __restrict__ fc_b,
    float* __restrict__ out, float* __restrict__ ws)
{
    const int dir = blockIdx.x & 1;
    const int b0  = (blockIdx.x >> 1) * SEQB;
    const int tid  = threadIdx.x;
    const int w    = tid >> 6;
    const int lane = tid & 63;
    const int hb   = lane >> 4;   // K-chunk owner (A/B), row-group (C/D)
    const int n    = lane & 15;   // seq column

    const float* __restrict__ Whh = dir ? Whh_b : Whh_f;
    const float* __restrict__ Wih = dir ? Wih_b : Wih_f;
    const float* __restrict__ bih = dir ? bih_b : bih_f;
    const float* __restrict__ bhh = dir ? bhh_b : bhh_f;

    __shared__ short Hlds[2][2][16][72];   // [buf][hi/lo][seq][h-row], 144B rows
    __shared__ float xs[16][TCH + 1];      // stride 129: conflict-free column read
    __shared__ float fcfb[2][16][4];       // [parity][seq][wave] FC partials
    __shared__ float os[SEQB][TT + 1];     // per-step FC results (LDS, no atomics)

    // Zero H (both buffers) and the never-written xs rows 8..15.
    {
        unsigned* p1 = (unsigned*)&Hlds[0][0][0][0];
        for (int i = tid; i < 2 * 2 * 16 * 72 / 2; i += 256) p1[i] = 0u;
        float* p2 = &xs[SEQB][0];
        for (int i = tid; i < (16 - SEQB) * (TCH + 1); i += 256) p2[i] = 0.f;
    }

    // A-fragments: lane holds A[row=lane&15][k=8*(lane>>4)+e], hi/lo bf16 split.
    short8 ahi[4][2], alo[4][2];
#pragma unroll
    for (int s = 0; s < 4; ++s)
#pragma unroll
        for (int kt = 0; kt < 2; ++kt) {
            const int zrow = 64 * s + 16 * w + n;
            const float* p = Whh + zrow * 64 + 32 * kt + 8 * hb;
            const float4 u0 = *(const float4*)p;
            const float4 u1 = *(const float4*)(p + 4);
            float v[8] = {u0.x, u0.y, u0.z, u0.w, u1.x, u1.y, u1.z, u1.w};
            short8 h8, l8;
#pragma unroll
            for (int e = 0; e < 8; ++e) {
                h8[e] = bhi(v[e]);
                l8[e] = bhi(v[e] - fhi(v[e]));
            }
            ahi[s][kt] = h8;
            alo[s][kt] = l8;
        }

    f32x4 biasv[4], wihv[4], fcwv;
#pragma unroll
    for (int s = 0; s < 4; ++s)
#pragma unroll
        for (int r = 0; r < 4; ++r) {
            const int row = 64 * s + 16 * w + 4 * hb + r;
            biasv[s][r] = bih[row] + bhh[row];
            wihv[s][r]  = Wih[row];
        }
#pragma unroll
    for (int r = 0; r < 4; ++r) fcwv[r] = fc_w[dir * 64 + 16 * w + 4 * hb + r];
    const float fcbv = dir ? 0.f : fc_b[0];

    // Pin loop-invariant fragments (R3/R4: compiler otherwise re-sinks loads).
    asm volatile("" : "+v"(ahi[0][0]), "+v"(ahi[0][1]), "+v"(ahi[1][0]), "+v"(ahi[1][1]),
                      "+v"(ahi[2][0]), "+v"(ahi[2][1]), "+v"(ahi[3][0]), "+v"(ahi[3][1]),
                      "+v"(alo[0][0]), "+v"(alo[0][1]), "+v"(alo[1][0]), "+v"(alo[1][1]),
                      "+v"(alo[2][0]), "+v"(alo[2][1]), "+v"(alo[3][0]), "+v"(alo[3][1]));
    asm volatile("" : "+v"(biasv[0]), "+v"(biasv[1]), "+v"(biasv[2]), "+v"(biasv[3]),
                      "+v"(wihv[0]), "+v"(wihv[1]), "+v"(wihv[2]), "+v"(wihv[3]), "+v"(fcwv));

    // First x tile. Bwd consumes x reversed; out index stays t.
    for (int idx = tid; idx < SEQB * TCH; idx += 256) {
        const int s = idx >> 7, i = idx & (TCH - 1);
        const int src = dir ? (TT - 1 - i) : i;
        xs[s][i] = x[(size_t)(b0 + s) * TT + src];
    }
    __syncthreads();

    f32x4 c = {0.f, 0.f, 0.f, 0.f};
    int cur = 0;

#pragma unroll 1
    for (int t = 0; t < TT; ++t) {
        if (t && (t & (TCH - 1)) == 0) {   // refill x tile (8x per kernel)
            for (int idx = tid; idx < SEQB * TCH; idx += 256) {
                const int s = idx >> 7, i = idx & (TCH - 1);
                const int tg = t + i;
                const int src = dir ? (TT - 1 - tg) : tg;
                xs[s][i] = x[(size_t)(b0 + s) * TT + src];
            }
            __syncthreads();
        }
        // Drain previous step's FC partials into LDS os (was: global atomicAdd;
        // that put an L2 round-trip inside every step's vmcnt(0) barrier drain).
        if (t && w == 0 && lane < SEQB) {
            const float4 fp = *(const float4*)&fcfb[(t - 1) & 1][lane][0];
            os[lane][t - 1] = fp.x + fp.y + fp.z + fp.w + fcbv;
        }

        // B-fragments: lane holds B[k=8*(lane>>4)+e][n=lane&15]; 1 b128/frag.
        short8 Bf[2][2];
#pragma unroll
        for (int kt = 0; kt < 2; ++kt)
#pragma unroll
            for (int pp = 0; pp < 2; ++pp)
                Bf[kt][pp] = *(const short8*)&Hlds[cur][pp][n][32 * kt + 8 * hb];

        const float xt = xs[n][t & (TCH - 1)];

        f32x4 acc0, acc1, acc2, acc3;
#define ZCHAIN(ACC, S)                                                              \
        ACC[0] = fmaf(xt, wihv[S][0], biasv[S][0]);                                 \
        ACC[1] = fmaf(xt, wihv[S][1], biasv[S][1]);                                 \
        ACC[2] = fmaf(xt, wihv[S][2], biasv[S][2]);                                 \
        ACC[3] = fmaf(xt, wihv[S][3], biasv[S][3]);                                 \
        ACC = __builtin_amdgcn_mfma_f32_16x16x32_bf16(ahi[S][0], Bf[0][0], ACC, 0, 0, 0); \
        ACC = __builtin_amdgcn_mfma_f32_16x16x32_bf16(ahi[S][0], Bf[0][1], ACC, 0, 0, 0); \
        ACC = __builtin_amdgcn_mfma_f32_16x16x32_bf16(alo[S][0], Bf[0][0], ACC, 0, 0, 0); \
        ACC = __builtin_amdgcn_mfma_f32_16x16x32_bf16(ahi[S][1], Bf[1][0], ACC, 0, 0, 0); \
        ACC = __builtin_amdgcn_mfma_f32_16x16x32_bf16(ahi[S][1], Bf[1][1], ACC, 0, 0, 0); \
        ACC = __builtin_amdgcn_mfma_f32_16x16x32_bf16(alo[S][1], Bf[1][0], ACC, 0, 0, 0);
        ZCHAIN(acc0, 0)   // gate i
        ZCHAIN(acc1, 1)   // gate f
        ZCHAIN(acc2, 2)   // gate g
        ZCHAIN(acc3, 3)   // gate o
#undef ZCHAIN

        // Gates + state update, fully in-register.
        f32x4 hnew;
        short4v ph, pl;
#pragma unroll
        for (int r = 0; r < 4; ++r) {
            const float gi = sigf(acc0[r]);
            const float gf = sigf(acc1[r]);
            const float gg = tanhf_(acc2[r]);
            const float go = sigf(acc3[r]);
            c[r] = fmaf(gf, c[r], gi * gg);
            const float hv = go * tanhf_(c[r]);
            hnew[r] = hv;
            ph[r] = bhi(hv);
            pl[r] = bhi(hv - fhi(hv));
        }
        const int nxt = cur ^ 1;
        *(short4v*)&Hlds[nxt][0][n][16 * w + 4 * hb] = ph;
        *(short4v*)&Hlds[nxt][1][n][16 * w + 4 * hb] = pl;

        // FC partial for this wave's 16 h-rows: reduce over hb groups.
        float d = hnew[0] * fcwv[0] + hnew[1] * fcwv[1] + hnew[2] * fcwv[2] + hnew[3] * fcwv[3];
        d += __shfl_xor(d, 16);
        d += __shfl_xor(d, 32);
        if (lane < 16) fcfb[t & 1][lane][w] = d;

        __syncthreads();
        cur = nxt;
    }

    // Final step's FC drain, then bulk-store os -> dst (coalesced float4).
    if (w == 0 && lane < SEQB) {
        const float4 fp = *(const float4*)&fcfb[(TT - 1) & 1][lane][0];
        os[lane][TT - 1] = fp.x + fp.y + fp.z + fp.w + fcbv;
    }
    __syncthreads();

    float* __restrict__ dst = dir ? ws : out;
#pragma unroll
    for (int s = 0; s < SEQB; ++s) {
        const int i = tid * 4;   // 256 threads x 4 floats = 1024 = one row
        *(float4*)(dst + (size_t)(b0 + s) * TT + i) = *(const float4*)&os[s][i];
    }
}

__global__ __launch_bounds__(256) void add_dirs(float* __restrict__ out,
                                                const float* __restrict__ ws, int n4) {
    const int i = (blockIdx.x * 256 + threadIdx.x);
    if (i < n4) {
        float4 a = ((const float4*)out)[i];
        const float4 b = ((const float4*)ws)[i];
        a.x += b.x; a.y += b.y; a.z += b.z; a.w += b.w;
        ((float4*)out)[i] = a;
    }
}

extern "C" void kernel_launch(void* const* d_in, const int* in_sizes, int n_in,
                              void* d_out, int out_size, void* d_ws, size_t ws_size,
                              hipStream_t stream) {
    const float* xp    = (const float*)d_in[0];
    const float* Wih_f = (const float*)d_in[1];
    const float* Whh_f = (const float*)d_in[2];
    const float* bih_f = (const float*)d_in[3];
    const float* bhh_f = (const float*)d_in[4];
    const float* Wih_b = (const float*)d_in[5];
    const float* Whh_b = (const float*)d_in[6];
    const float* bih_b = (const float*)d_in[7];
    const float* bhh_b = (const float*)d_in[8];
    const float* fc_w  = (const float*)d_in[9];
    const float* fc_b  = (const float*)d_in[10];
    float* outp = (float*)d_out;
    float* wsp  = (float*)d_ws;   // bwd-direction partials (fully written before read)

    // No memset needed: fwd blocks store every out element; bwd fully writes ws.
    bilstm_mfma<<<dim3((1024 / SEQB) * 2), dim3(256), 0, stream>>>(
        xp, Wih_f, Whh_f, bih_f, bhh_f,
        Wih_b, Whh_b, bih_b, bhh_b, fc_w, fc_b, outp, wsp);

    const int n4 = out_size / 4;   // 1M floats -> 256K float4s
    add_dirs<<<dim3((n4 + 255) / 256), dim3(256), 0, stream>>>(outp, wsp, n4);
}